// Round 1
// baseline (3687.475 us; speedup 1.0000x reference)
//
#include <hip/hip_runtime.h>
#include <math.h>

#define BB 2
#define SS 2048
#define EE 2048
#define HH 16
#define KVHH 4
#define DD 128
#define GG (HH / KVHH)
#define SCALE 0.08838834764831843f

// ---------------------------------------------------------------------------
// GEMM: C[M,N] = A[M,K] @ W[N,K]^T   (A row-major MxK, W row-major NxK)
// 64x64 tile, BK=16, 256 threads, 4x4 micro-tile per thread, fp32.
// ---------------------------------------------------------------------------
__global__ __launch_bounds__(256) void gemm_bt(const float* __restrict__ A,
                                               const float* __restrict__ W,
                                               float* __restrict__ C,
                                               int M, int N, int K) {
    __shared__ float As[16][68];   // [k][m], row stride 68 floats (16B aligned rows)
    __shared__ float Bs[16][68];   // [k][n]
    const int tid = threadIdx.x;
    const int tn = tid & 15;        // 0..15
    const int tm = tid >> 4;        // 0..15
    const int m0 = blockIdx.y * 64;
    const int n0 = blockIdx.x * 64;
    const int lr = tid >> 2;        // 0..63 (tile row for loading)
    const int lc = (tid & 3) * 4;   // 0,4,8,12 (k offset for loading)

    float acc[4][4] = {};

    for (int k0 = 0; k0 < K; k0 += 16) {
        float4 av = *(const float4*)&A[(long)(m0 + lr) * K + k0 + lc];
        float4 wv = *(const float4*)&W[(long)(n0 + lr) * K + k0 + lc];
        __syncthreads();   // protect LDS from previous iteration's readers
        As[lc + 0][lr] = av.x; As[lc + 1][lr] = av.y;
        As[lc + 2][lr] = av.z; As[lc + 3][lr] = av.w;
        Bs[lc + 0][lr] = wv.x; Bs[lc + 1][lr] = wv.y;
        Bs[lc + 2][lr] = wv.z; Bs[lc + 3][lr] = wv.w;
        __syncthreads();
#pragma unroll
        for (int kk = 0; kk < 16; ++kk) {
            float4 a = *(const float4*)&As[kk][tm * 4];
            float4 b = *(const float4*)&Bs[kk][tn * 4];
            float ar[4] = {a.x, a.y, a.z, a.w};
            float br[4] = {b.x, b.y, b.z, b.w};
#pragma unroll
            for (int i = 0; i < 4; ++i)
#pragma unroll
                for (int j = 0; j < 4; ++j)
                    acc[i][j] += ar[i] * br[j];
        }
    }
#pragma unroll
    for (int i = 0; i < 4; ++i)
#pragma unroll
        for (int j = 0; j < 4; ++j)
            C[(long)(m0 + tm * 4 + i) * N + n0 + tn * 4 + j] = acc[i][j];
}

// ---------------------------------------------------------------------------
// Flash-style causal attention, fp32.
// Q stored [B,S,H,D]; K,V stored [B,S,KVH,D]; ctx out [B,S,H,D].
// One block per (q_chunk=32 rows, head, batch). 256 threads.
// Score layout: thread t -> col c = t%32, rows r = (t/32)*4 + i (i<4).
// PV layout:    thread t -> d = t%128,  rows r = (t/128)*16 + i (i<16).
// ---------------------------------------------------------------------------
__global__ __launch_bounds__(256) void attn_kernel(const float* __restrict__ Q,
                                                   const float* __restrict__ Kp,
                                                   const float* __restrict__ Vp,
                                                   float* __restrict__ ctx) {
    __shared__ float Qs[32][129];
    __shared__ float Ks[32][129];
    __shared__ float Vs[32][129];
    __shared__ float Ps[32][33];
    __shared__ float alpha_s[32];
    __shared__ float l_s[32];

    const int tid = threadIdx.x;
    const int qc = blockIdx.x;      // query chunk (32 rows)
    const int h  = blockIdx.y;
    const int b  = blockIdx.z;
    const int kvh = h / GG;
    const int q0 = qc * 32;

    // ---- load Q tile, pre-scaled by 1/sqrt(D) ----
#pragma unroll
    for (int p = 0; p < 4; ++p) {
        int idx = p * 256 + tid;
        int r = idx >> 5;                // 0..31
        int c4 = (idx & 31) * 4;         // 0..124
        float4 qv = *(const float4*)&Q[((long)(b * SS + q0 + r) * HH + h) * DD + c4];
        Qs[r][c4 + 0] = qv.x * SCALE;
        Qs[r][c4 + 1] = qv.y * SCALE;
        Qs[r][c4 + 2] = qv.z * SCALE;
        Qs[r][c4 + 3] = qv.w * SCALE;
    }

    const int c = tid & 31;              // score column
    const int rg = tid >> 5;             // row group 0..7 -> rows rg*4..rg*4+3
    const int dcol = tid & 127;          // PV d
    const int rbase = (tid >> 7) * 16;   // PV row base (0 or 16)

    float m_i[4], l_i[4];
#pragma unroll
    for (int i = 0; i < 4; ++i) { m_i[i] = -INFINITY; l_i[i] = 0.f; }
    float O[16];
#pragma unroll
    for (int i = 0; i < 16; ++i) O[i] = 0.f;

    for (int kt = 0; kt <= qc; ++kt) {
        __syncthreads();   // prior iteration readers of Ks/Vs/Ps done
        // ---- load K/V tile ----
#pragma unroll
        for (int p = 0; p < 4; ++p) {
            int idx = p * 256 + tid;
            int r = idx >> 5;
            int c4 = (idx & 31) * 4;
            long base = ((long)(b * SS + kt * 32 + r) * KVHH + kvh) * DD + c4;
            float4 kv = *(const float4*)&Kp[base];
            float4 vv = *(const float4*)&Vp[base];
            Ks[r][c4 + 0] = kv.x; Ks[r][c4 + 1] = kv.y;
            Ks[r][c4 + 2] = kv.z; Ks[r][c4 + 3] = kv.w;
            Vs[r][c4 + 0] = vv.x; Vs[r][c4 + 1] = vv.y;
            Vs[r][c4 + 2] = vv.z; Vs[r][c4 + 3] = vv.w;
        }
        __syncthreads();

        // ---- scores: acc[i] = Qs[rg*4+i] . Ks[c] ----
        float acc[4] = {0.f, 0.f, 0.f, 0.f};
        for (int k = 0; k < DD; ++k) {
            float kv = Ks[c][k];
#pragma unroll
            for (int i = 0; i < 4; ++i)
                acc[i] += Qs[rg * 4 + i][k] * kv;
        }

        const bool diag = (kt == qc);
#pragma unroll
        for (int i = 0; i < 4; ++i) {
            int r = rg * 4 + i;
            float v = acc[i];
            if (diag && c > r) v = -INFINITY;
            // row max over the 32 lanes holding this row (xor<32 stays in half-wave)
            float mx = v;
#pragma unroll
            for (int off = 1; off < 32; off <<= 1)
                mx = fmaxf(mx, __shfl_xor(mx, off, 64));
            float m_new = fmaxf(m_i[i], mx);     // always finite (diag elem valid)
            float pe = __expf(v - m_new);        // masked -> 0
            float sum = pe;
#pragma unroll
            for (int off = 1; off < 32; off <<= 1)
                sum += __shfl_xor(sum, off, 64);
            float alpha = __expf(m_i[i] - m_new); // first tile: exp(-inf)=0
            l_i[i] = l_i[i] * alpha + sum;
            m_i[i] = m_new;
            Ps[r][c] = pe;
            if (c == 0) alpha_s[r] = alpha;
        }
        __syncthreads();

        // ---- PV: O[r][d] = O*alpha + sum_c Ps[r][c]*Vs[c][d] ----
#pragma unroll
        for (int i = 0; i < 16; ++i) O[i] *= alpha_s[rbase + i];
        for (int cc = 0; cc < 32; ++cc) {
            float vv = Vs[cc][dcol];
#pragma unroll
            for (int i = 0; i < 16; ++i)
                O[i] += Ps[rbase + i][cc] * vv;
        }
    }

    __syncthreads();
    if (c == 0) {
#pragma unroll
        for (int i = 0; i < 4; ++i) l_s[rg * 4 + i] = l_i[i];
    }
    __syncthreads();

#pragma unroll
    for (int i = 0; i < 16; ++i) {
        int r = rbase + i;
        ctx[((long)(b * SS + q0 + r) * HH + h) * DD + dcol] = O[i] / l_s[r];
    }
}

// ---------------------------------------------------------------------------
extern "C" void kernel_launch(void* const* d_in, const int* in_sizes, int n_in,
                              void* d_out, int out_size, void* d_ws, size_t ws_size,
                              hipStream_t stream) {
    const float* x  = (const float*)d_in[0];   // [B,S,E]
    const float* Wq = (const float*)d_in[1];   // [E,E]
    const float* Wk = (const float*)d_in[2];   // [KVH*D, E]
    const float* Wv = (const float*)d_in[3];   // [KVH*D, E]
    const float* Wo = (const float*)d_in[4];   // [E,E]
    float* out = (float*)d_out;                // [B,S,E]

    const int M = BB * SS;                     // 4096
    float* Qp  = (float*)d_ws;                       // M*E
    float* Kp  = Qp + (size_t)M * EE;                // M*KVH*D
    float* Vp  = Kp + (size_t)M * KVHH * DD;         // M*KVH*D
    float* ctx = Vp + (size_t)M * KVHH * DD;         // M*E

    dim3 blk(256);
    // Q = x @ Wq^T   -> [B,S,H,D] flat as [M, E]
    gemm_bt<<<dim3(EE / 64, M / 64), blk, 0, stream>>>(x, Wq, Qp, M, EE, EE);
    // K = x @ Wk^T, V = x @ Wv^T -> [M, KVH*D]
    gemm_bt<<<dim3((KVHH * DD) / 64, M / 64), blk, 0, stream>>>(x, Wk, Kp, M, KVHH * DD, EE);
    gemm_bt<<<dim3((KVHH * DD) / 64, M / 64), blk, 0, stream>>>(x, Wv, Vp, M, KVHH * DD, EE);
    // causal GQA attention
    attn_kernel<<<dim3(SS / 32, HH, BB), blk, 0, stream>>>(Qp, Kp, Vp, ctx);
    // out = ctx @ Wo^T
    gemm_bt<<<dim3(EE / 64, M / 64), blk, 0, stream>>>(ctx, Wo, out, M, EE, EE);
}

// Round 2
// 1490.950 us; speedup vs baseline: 2.4732x; 2.4732x over previous
//
#include <hip/hip_runtime.h>
#include <math.h>

#define BB 2
#define SS 2048
#define EE 2048
#define HH 16
#define KVHH 4
#define DD 128
#define GG (HH / KVHH)
#define KVN (KVHH * DD)   // 512
#define SCALE 0.08838834764831843f

typedef __attribute__((ext_vector_type(8))) short bf16x8;
typedef __attribute__((ext_vector_type(4))) float f32x4;

__device__ __forceinline__ unsigned short f2bf(float f) {
    union { float f; unsigned int u; } x; x.f = f;
    unsigned int r = x.u + 0x7fff + ((x.u >> 16) & 1);   // RNE
    return (unsigned short)(r >> 16);
}

// ---------------------------------------------------------------------------
// GEMM: C[M,N] = A[M,K] @ W[N,K]^T  (fp32 accumulate). Three epilogues:
//   mode 0: fp32 row-major C
//   mode 1: bf16 row-major C
//   mode 2: bf16 transposed-V layout: C[(b*KVH+kvh)*D + d][s]  (b,s from m; kvh,d from n)
// 64x64 tile, BK=16, 256 threads, 4x4 micro-tile.
// ---------------------------------------------------------------------------
template <int MODE>
__global__ __launch_bounds__(256) void gemm_bt(const float* __restrict__ A,
                                               const float* __restrict__ W,
                                               void* __restrict__ Cv,
                                               int M, int N, int K) {
    __shared__ float As[16][68];
    __shared__ float Bs[16][68];
    const int tid = threadIdx.x;
    const int tn = tid & 15;
    const int tm = tid >> 4;
    const int m0 = blockIdx.y * 64;
    const int n0 = blockIdx.x * 64;
    const int lr = tid >> 2;
    const int lc = (tid & 3) * 4;

    float acc[4][4] = {};

    for (int k0 = 0; k0 < K; k0 += 16) {
        float4 av = *(const float4*)&A[(long)(m0 + lr) * K + k0 + lc];
        float4 wv = *(const float4*)&W[(long)(n0 + lr) * K + k0 + lc];
        __syncthreads();
        As[lc + 0][lr] = av.x; As[lc + 1][lr] = av.y;
        As[lc + 2][lr] = av.z; As[lc + 3][lr] = av.w;
        Bs[lc + 0][lr] = wv.x; Bs[lc + 1][lr] = wv.y;
        Bs[lc + 2][lr] = wv.z; Bs[lc + 3][lr] = wv.w;
        __syncthreads();
#pragma unroll
        for (int kk = 0; kk < 16; ++kk) {
            float4 a = *(const float4*)&As[kk][tm * 4];
            float4 b = *(const float4*)&Bs[kk][tn * 4];
            float ar[4] = {a.x, a.y, a.z, a.w};
            float br[4] = {b.x, b.y, b.z, b.w};
#pragma unroll
            for (int i = 0; i < 4; ++i)
#pragma unroll
                for (int j = 0; j < 4; ++j)
                    acc[i][j] += ar[i] * br[j];
        }
    }

    if (MODE == 0) {
        float* C = (float*)Cv;
#pragma unroll
        for (int i = 0; i < 4; ++i)
#pragma unroll
            for (int j = 0; j < 4; ++j)
                C[(long)(m0 + tm * 4 + i) * N + n0 + tn * 4 + j] = acc[i][j];
    } else if (MODE == 1) {
        unsigned short* C = (unsigned short*)Cv;
#pragma unroll
        for (int i = 0; i < 4; ++i) {
            ushort4 p;
            p.x = f2bf(acc[i][0]); p.y = f2bf(acc[i][1]);
            p.z = f2bf(acc[i][2]); p.w = f2bf(acc[i][3]);
            *(ushort4*)&C[(long)(m0 + tm * 4 + i) * N + n0 + tn * 4] = p;
        }
    } else {
        // transposed V: addr = (b*KVN + n)*S + s
        unsigned short* C = (unsigned short*)Cv;
        const int mb = m0 + tm * 4;
        const int bb = mb >> 11;            // / S
        const int s  = mb & (SS - 1);
#pragma unroll
        for (int j = 0; j < 4; ++j) {
            int n = n0 + tn * 4 + j;
            ushort4 p;
            p.x = f2bf(acc[0][j]); p.y = f2bf(acc[1][j]);
            p.z = f2bf(acc[2][j]); p.w = f2bf(acc[3][j]);
            *(ushort4*)&C[((long)(bb * KVN + n)) * SS + s] = p;
        }
    }
}

// ---------------------------------------------------------------------------
// Flash-style causal GQA attention with bf16 MFMA (16x16x32).
// Qg: bf16 [B*S, E] (row-major, head h at col h*D)
// Kg: bf16 [B*S, KVN]
// VtG: bf16 [(b*KVH+kvh)*D + d][S]  (V transposed per kv-head)
// ctx: fp32 [B*S, E]
// Block: 64 q-rows x one head. 256 threads = 4 waves; wave w owns q rows w*16..+15.
// ---------------------------------------------------------------------------
#define QSTR 136
#define KSTR 136
#define VSTR 72
#define PSTR 72

__global__ __launch_bounds__(256) void attn_mfma(const unsigned short* __restrict__ Qg,
                                                 const unsigned short* __restrict__ Kg,
                                                 const unsigned short* __restrict__ VtG,
                                                 float* __restrict__ ctx) {
    __shared__ unsigned short Qs[64 * QSTR];
    __shared__ unsigned short Ks[64 * KSTR];
    __shared__ unsigned short Vt[128 * VSTR];
    __shared__ unsigned short Ps[64 * PSTR];

    const int tid  = threadIdx.x;
    const int w    = tid >> 6;
    const int lane = tid & 63;
    const int l16  = lane & 15;
    const int quad = lane >> 4;
    const int qc = blockIdx.x;
    const int h  = blockIdx.y;
    const int b  = blockIdx.z;
    const int kvh = h / GG;
    const int q0 = qc * 64;

    // ---- stage Q tile (64 x 128 bf16) ----
#pragma unroll
    for (int p = 0; p < 4; ++p) {
        int idx = p * 256 + tid;
        int r  = idx >> 4;
        int c8 = (idx & 15) * 8;
        float4 v = *(const float4*)(Qg + (size_t)(b * SS + q0 + r) * EE + h * DD + c8);
        *(float4*)&Qs[r * QSTR + c8] = v;
    }
    __syncthreads();

    // ---- Q A-fragments into registers (fixed for whole block) ----
    bf16x8 Qa[4];
    const int qrow = w * 16 + l16;
#pragma unroll
    for (int kd = 0; kd < 4; ++kd)
        Qa[kd] = *(const bf16x8*)&Qs[qrow * QSTR + kd * 32 + quad * 8];

    float m_i[4], l_i[4];
#pragma unroll
    for (int i = 0; i < 4; ++i) { m_i[i] = -INFINITY; l_i[i] = 0.f; }
    f32x4 acc_o[8];
#pragma unroll
    for (int i = 0; i < 8; ++i) acc_o[i] = (f32x4){0.f, 0.f, 0.f, 0.f};

    const int qglob = q0 + w * 16 + quad * 4;   // + reg

    for (int kt = 0; kt <= qc; ++kt) {
        __syncthreads();   // previous iteration's readers of Ks/Vt/Ps done
        // ---- stage K tile (64 x 128) ----
#pragma unroll
        for (int p = 0; p < 4; ++p) {
            int idx = p * 256 + tid;
            int r  = idx >> 4;
            int c8 = (idx & 15) * 8;
            float4 v = *(const float4*)(Kg + (size_t)(b * SS + kt * 64 + r) * KVN + kvh * DD + c8);
            *(float4*)&Ks[r * KSTR + c8] = v;
        }
        // ---- stage Vt tile (128 d-rows x 64 kk) ----
#pragma unroll
        for (int p = 0; p < 4; ++p) {
            int idx = p * 256 + tid;
            int r  = idx >> 3;            // d row 0..127
            int c8 = (idx & 7) * 8;       // 0..56
            float4 v = *(const float4*)(VtG + ((size_t)((b * KVHH + kvh) * DD + r)) * SS + kt * 64 + c8);
            *(float4*)&Vt[r * VSTR + c8] = v;
        }
        __syncthreads();

        // ---- scores S = Q K^T (per wave: 16 q-rows x 64 kk) ----
        f32x4 sc[4];
#pragma unroll
        for (int kkt = 0; kkt < 4; ++kkt) {
            f32x4 a = (f32x4){0.f, 0.f, 0.f, 0.f};
#pragma unroll
            for (int kd = 0; kd < 4; ++kd) {
                bf16x8 kb = *(const bf16x8*)&Ks[(kkt * 16 + l16) * KSTR + kd * 32 + quad * 8];
                a = __builtin_amdgcn_mfma_f32_16x16x32_bf16(Qa[kd], kb, a, 0, 0, 0);
            }
            sc[kkt] = a;
        }

        // ---- online softmax (C layout: row = quad*4+reg, col = kkt*16+l16) ----
        const int kbase = kt * 64 + l16;
        float alpha[4];
#pragma unroll
        for (int reg = 0; reg < 4; ++reg) {
            float rowmax = -INFINITY;
#pragma unroll
            for (int kkt = 0; kkt < 4; ++kkt) {
                float v = sc[kkt][reg] * SCALE;
                if (kbase + kkt * 16 > qglob + reg) v = -INFINITY;
                sc[kkt][reg] = v;
                rowmax = fmaxf(rowmax, v);
            }
#pragma unroll
            for (int off = 1; off < 16; off <<= 1)
                rowmax = fmaxf(rowmax, __shfl_xor(rowmax, off, 64));
            float mnew = fmaxf(m_i[reg], rowmax);
            float rsum = 0.f;
#pragma unroll
            for (int kkt = 0; kkt < 4; ++kkt) {
                float p = __expf(sc[kkt][reg] - mnew);
                sc[kkt][reg] = p;
                rsum += p;
            }
#pragma unroll
            for (int off = 1; off < 16; off <<= 1)
                rsum += __shfl_xor(rsum, off, 64);
            alpha[reg] = __expf(m_i[reg] - mnew);
            l_i[reg] = l_i[reg] * alpha[reg] + rsum;
            m_i[reg] = mnew;
        }

        // ---- write P to LDS (bf16, row-major [q][kk]) for A-layout reload ----
#pragma unroll
        for (int reg = 0; reg < 4; ++reg)
#pragma unroll
            for (int kkt = 0; kkt < 4; ++kkt)
                Ps[(w * 16 + quad * 4 + reg) * PSTR + kkt * 16 + l16] = f2bf(sc[kkt][reg]);
        __syncthreads();

        // ---- rescale O ----
#pragma unroll
        for (int dt = 0; dt < 8; ++dt)
#pragma unroll
            for (int reg = 0; reg < 4; ++reg)
                acc_o[dt][reg] *= alpha[reg];

        // ---- O += P V ----
#pragma unroll
        for (int ks = 0; ks < 2; ++ks) {
            bf16x8 pa = *(const bf16x8*)&Ps[(w * 16 + l16) * PSTR + ks * 32 + quad * 8];
#pragma unroll
            for (int dt = 0; dt < 8; ++dt) {
                bf16x8 vb = *(const bf16x8*)&Vt[(dt * 16 + l16) * VSTR + ks * 32 + quad * 8];
                acc_o[dt] = __builtin_amdgcn_mfma_f32_16x16x32_bf16(pa, vb, acc_o[dt], 0, 0, 0);
            }
        }
    }

    // ---- epilogue: O / l, fp32 out ----
    float linv[4];
#pragma unroll
    for (int reg = 0; reg < 4; ++reg) linv[reg] = 1.f / l_i[reg];
#pragma unroll
    for (int dt = 0; dt < 8; ++dt)
#pragma unroll
        for (int reg = 0; reg < 4; ++reg)
            ctx[(size_t)(b * SS + q0 + w * 16 + quad * 4 + reg) * EE + h * DD + dt * 16 + l16] =
                acc_o[dt][reg] * linv[reg];
}

// ---------------------------------------------------------------------------
extern "C" void kernel_launch(void* const* d_in, const int* in_sizes, int n_in,
                              void* d_out, int out_size, void* d_ws, size_t ws_size,
                              hipStream_t stream) {
    const float* x  = (const float*)d_in[0];
    const float* Wq = (const float*)d_in[1];
    const float* Wk = (const float*)d_in[2];
    const float* Wv = (const float*)d_in[3];
    const float* Wo = (const float*)d_in[4];
    float* out = (float*)d_out;

    const int M = BB * SS;                        // 4096
    unsigned short* Qg  = (unsigned short*)d_ws;                  // M*E bf16
    unsigned short* Kg  = Qg + (size_t)M * EE;                    // M*KVN bf16
    unsigned short* VtG = Kg + (size_t)M * KVN;                   // M*KVN bf16 (transposed layout)
    float* ctx = (float*)(VtG + (size_t)M * KVN);                 // M*E fp32

    dim3 blk(256);
    gemm_bt<1><<<dim3(EE / 64, M / 64), blk, 0, stream>>>(x, Wq, Qg, M, EE, EE);
    gemm_bt<1><<<dim3(KVN / 64, M / 64), blk, 0, stream>>>(x, Wk, Kg, M, KVN, EE);
    gemm_bt<2><<<dim3(KVN / 64, M / 64), blk, 0, stream>>>(x, Wv, VtG, M, KVN, EE);
    attn_mfma<<<dim3(SS / 64, HH, BB), blk, 0, stream>>>(Qg, Kg, VtG, ctx);
    gemm_bt<0><<<dim3(EE / 64, M / 64), blk, 0, stream>>>(ctx, Wo, out, M, EE, EE);
}

// Round 3
// 505.043 us; speedup vs baseline: 7.3013x; 2.9521x over previous
//
#include <hip/hip_runtime.h>
#include <math.h>

#define BB 2
#define SS 2048
#define EE 2048
#define HH 16
#define KVHH 4
#define DD 128
#define GG (HH / KVHH)
#define KVN (KVHH * DD)   // 512
#define SCALE 0.08838834764831843f

typedef __attribute__((ext_vector_type(8))) short bf16x8;
typedef __attribute__((ext_vector_type(4))) float f32x4;
typedef unsigned short u16;
typedef unsigned int u32;

__device__ __forceinline__ u16 f2bf(float f) {
    union { float f; u32 u; } x; x.f = f;
    u32 r = x.u + 0x7fff + ((x.u >> 16) & 1);   // RNE
    return (u16)(r >> 16);
}

__device__ __forceinline__ void gload_lds16(const void* g, void* l) {
    __builtin_amdgcn_global_load_lds(
        (const __attribute__((address_space(1))) u32*)g,
        (__attribute__((address_space(3))) u32*)l, 16, 0, 0);
}

// ---------------------------------------------------------------------------
// fp32 -> bf16 cast, vectorized
// ---------------------------------------------------------------------------
__global__ __launch_bounds__(256) void cast_bf16(const float* __restrict__ in,
                                                 u16* __restrict__ out, int n) {
    int i = (blockIdx.x * 256 + threadIdx.x) * 4;
    if (i < n) {
        float4 v = *(const float4*)&in[i];
        ushort4 o;
        o.x = f2bf(v.x); o.y = f2bf(v.y); o.z = f2bf(v.z); o.w = f2bf(v.w);
        *(ushort4*)&out[i] = o;
    }
}

// ---------------------------------------------------------------------------
// m97-structure MFMA GEMM: C[M,N] = A[M,K] @ B[N,K]^T, A/B bf16, fp32 acc.
// 128x128 tile, BK=32, 256 threads = 4 waves (2x2), 4x4 16x16x32 MFMAs/wave.
// global->LDS via global_load_lds width=16 (unpadded LDS, wave-uniform base).
// MODE 0: fp32 row-major C;  MODE 1: bf16 row-major C;
// MODE 2: bf16 transposed-V: C[(b*KVN + n)*S + s], m = b*S+s.
// ---------------------------------------------------------------------------
template <int MODE>
__global__ __launch_bounds__(256) void gemm_mfma(const u16* __restrict__ A,
                                                 const u16* __restrict__ B,
                                                 void* __restrict__ Cv,
                                                 int M, int N, int K) {
    __shared__ __align__(16) u16 As[128 * 32];
    __shared__ __align__(16) u16 Bs[128 * 32];
    const int tid  = threadIdx.x;
    const int w    = tid >> 6;
    const int lane = tid & 63;
    const int l16  = lane & 15;
    const int quad = lane >> 4;
    const int wm = (w >> 1) * 64;
    const int wn = (w & 1) * 64;
    const int m0 = blockIdx.y * 128;
    const int n0 = blockIdx.x * 128;

    // staging chunks: chunk c (0..511) covers row c>>2, k-offset (c&3)*8
    const int r0 = tid >> 2,           ko0 = (tid & 3) * 8;
    const int r1 = (256 + tid) >> 2,   ko1 = (tid & 3) * 8;
    u16* ldsA0 = &As[(size_t)(w * 64) * 8];
    u16* ldsA1 = &As[(size_t)(256 + w * 64) * 8];
    u16* ldsB0 = &Bs[(size_t)(w * 64) * 8];
    u16* ldsB1 = &Bs[(size_t)(256 + w * 64) * 8];

    f32x4 acc[4][4];
#pragma unroll
    for (int i = 0; i < 4; ++i)
#pragma unroll
        for (int j = 0; j < 4; ++j) acc[i][j] = (f32x4){0.f, 0.f, 0.f, 0.f};

    for (int k0 = 0; k0 < K; k0 += 32) {
        __syncthreads();
        gload_lds16(A + (size_t)(m0 + r0) * K + k0 + ko0, ldsA0);
        gload_lds16(A + (size_t)(m0 + r1) * K + k0 + ko1, ldsA1);
        gload_lds16(B + (size_t)(n0 + r0) * K + k0 + ko0, ldsB0);
        gload_lds16(B + (size_t)(n0 + r1) * K + k0 + ko1, ldsB1);
        __syncthreads();

        bf16x8 af[4], bfr[4];
#pragma unroll
        for (int i = 0; i < 4; ++i)
            af[i] = *(const bf16x8*)&As[(wm + i * 16 + l16) * 32 + quad * 8];
#pragma unroll
        for (int j = 0; j < 4; ++j)
            bfr[j] = *(const bf16x8*)&Bs[(wn + j * 16 + l16) * 32 + quad * 8];
#pragma unroll
        for (int i = 0; i < 4; ++i)
#pragma unroll
            for (int j = 0; j < 4; ++j)
                acc[i][j] = __builtin_amdgcn_mfma_f32_16x16x32_bf16(af[i], bfr[j], acc[i][j], 0, 0, 0);
    }

    if (MODE == 0) {
        float* C = (float*)Cv;
#pragma unroll
        for (int i = 0; i < 4; ++i)
#pragma unroll
            for (int j = 0; j < 4; ++j)
#pragma unroll
                for (int reg = 0; reg < 4; ++reg)
                    C[(size_t)(m0 + wm + i * 16 + quad * 4 + reg) * N + n0 + wn + j * 16 + l16] =
                        acc[i][j][reg];
    } else if (MODE == 1) {
        u16* C = (u16*)Cv;
#pragma unroll
        for (int i = 0; i < 4; ++i)
#pragma unroll
            for (int j = 0; j < 4; ++j)
#pragma unroll
                for (int reg = 0; reg < 4; ++reg)
                    C[(size_t)(m0 + wm + i * 16 + quad * 4 + reg) * N + n0 + wn + j * 16 + l16] =
                        f2bf(acc[i][j][reg]);
    } else {
        u16* C = (u16*)Cv;
#pragma unroll
        for (int i = 0; i < 4; ++i) {
            const int m = m0 + wm + i * 16 + quad * 4;   // multiple of 4; +reg
            const int bb = m >> 11;
            const int s  = m & (SS - 1);
#pragma unroll
            for (int j = 0; j < 4; ++j) {
                const int n = n0 + wn + j * 16 + l16;
                ushort4 p;
                p.x = f2bf(acc[i][j][0]); p.y = f2bf(acc[i][j][1]);
                p.z = f2bf(acc[i][j][2]); p.w = f2bf(acc[i][j][3]);
                *(ushort4*)&C[((size_t)(bb * KVN + n)) * SS + s] = p;
            }
        }
    }
}

// ---------------------------------------------------------------------------
// Flash-style causal GQA attention with bf16 MFMA (16x16x32).
// Qg bf16 [B*S,E]; Kg bf16 [B*S,KVN]; VtG bf16 [(b*KVH+kvh)*D + d][S];
// ctx OUT bf16 [B*S,E].
// Block: 64 q-rows x one head. 256 threads = 4 waves; wave w owns q rows w*16..+15.
// ---------------------------------------------------------------------------
#define QSTR 136
#define KSTR 136
#define VSTR 72
#define PSTR 72

__global__ __launch_bounds__(256) void attn_mfma(const u16* __restrict__ Qg,
                                                 const u16* __restrict__ Kg,
                                                 const u16* __restrict__ VtG,
                                                 u16* __restrict__ ctx) {
    __shared__ __align__(16) u16 Qs[64 * QSTR];
    __shared__ __align__(16) u16 Ks[64 * KSTR];
    __shared__ __align__(16) u16 Vt[128 * VSTR];
    __shared__ __align__(16) u16 Ps[64 * PSTR];

    const int tid  = threadIdx.x;
    const int w    = tid >> 6;
    const int lane = tid & 63;
    const int l16  = lane & 15;
    const int quad = lane >> 4;
    const int qc = blockIdx.x;
    const int h  = blockIdx.y;
    const int b  = blockIdx.z;
    const int kvh = h / GG;
    const int q0 = qc * 64;

#pragma unroll
    for (int p = 0; p < 4; ++p) {
        int idx = p * 256 + tid;
        int r  = idx >> 4;
        int c8 = (idx & 15) * 8;
        float4 v = *(const float4*)(Qg + (size_t)(b * SS + q0 + r) * EE + h * DD + c8);
        *(float4*)&Qs[r * QSTR + c8] = v;
    }
    __syncthreads();

    bf16x8 Qa[4];
    const int qrow = w * 16 + l16;
#pragma unroll
    for (int kd = 0; kd < 4; ++kd)
        Qa[kd] = *(const bf16x8*)&Qs[qrow * QSTR + kd * 32 + quad * 8];

    float m_i[4], l_i[4];
#pragma unroll
    for (int i = 0; i < 4; ++i) { m_i[i] = -INFINITY; l_i[i] = 0.f; }
    f32x4 acc_o[8];
#pragma unroll
    for (int i = 0; i < 8; ++i) acc_o[i] = (f32x4){0.f, 0.f, 0.f, 0.f};

    const int qglob = q0 + w * 16 + quad * 4;

    for (int kt = 0; kt <= qc; ++kt) {
        __syncthreads();
#pragma unroll
        for (int p = 0; p < 4; ++p) {
            int idx = p * 256 + tid;
            int r  = idx >> 4;
            int c8 = (idx & 15) * 8;
            float4 v = *(const float4*)(Kg + (size_t)(b * SS + kt * 64 + r) * KVN + kvh * DD + c8);
            *(float4*)&Ks[r * KSTR + c8] = v;
        }
#pragma unroll
        for (int p = 0; p < 4; ++p) {
            int idx = p * 256 + tid;
            int r  = idx >> 3;
            int c8 = (idx & 7) * 8;
            float4 v = *(const float4*)(VtG + ((size_t)((b * KVHH + kvh) * DD + r)) * SS + kt * 64 + c8);
            *(float4*)&Vt[r * VSTR + c8] = v;
        }
        __syncthreads();

        f32x4 sc[4];
#pragma unroll
        for (int kkt = 0; kkt < 4; ++kkt) {
            f32x4 a = (f32x4){0.f, 0.f, 0.f, 0.f};
#pragma unroll
            for (int kd = 0; kd < 4; ++kd) {
                bf16x8 kb = *(const bf16x8*)&Ks[(kkt * 16 + l16) * KSTR + kd * 32 + quad * 8];
                a = __builtin_amdgcn_mfma_f32_16x16x32_bf16(Qa[kd], kb, a, 0, 0, 0);
            }
            sc[kkt] = a;
        }

        const int kbase = kt * 64 + l16;
        float alpha[4];
#pragma unroll
        for (int reg = 0; reg < 4; ++reg) {
            float rowmax = -INFINITY;
#pragma unroll
            for (int kkt = 0; kkt < 4; ++kkt) {
                float v = sc[kkt][reg] * SCALE;
                if (kbase + kkt * 16 > qglob + reg) v = -INFINITY;
                sc[kkt][reg] = v;
                rowmax = fmaxf(rowmax, v);
            }
#pragma unroll
            for (int off = 1; off < 16; off <<= 1)
                rowmax = fmaxf(rowmax, __shfl_xor(rowmax, off, 64));
            float mnew = fmaxf(m_i[reg], rowmax);
            float rsum = 0.f;
#pragma unroll
            for (int kkt = 0; kkt < 4; ++kkt) {
                float p = __expf(sc[kkt][reg] - mnew);
                sc[kkt][reg] = p;
                rsum += p;
            }
#pragma unroll
            for (int off = 1; off < 16; off <<= 1)
                rsum += __shfl_xor(rsum, off, 64);
            alpha[reg] = __expf(m_i[reg] - mnew);
            l_i[reg] = l_i[reg] * alpha[reg] + rsum;
            m_i[reg] = mnew;
        }

#pragma unroll
        for (int reg = 0; reg < 4; ++reg)
#pragma unroll
            for (int kkt = 0; kkt < 4; ++kkt)
                Ps[(w * 16 + quad * 4 + reg) * PSTR + kkt * 16 + l16] = f2bf(sc[kkt][reg]);
        __syncthreads();

#pragma unroll
        for (int dt = 0; dt < 8; ++dt)
#pragma unroll
            for (int reg = 0; reg < 4; ++reg)
                acc_o[dt][reg] *= alpha[reg];

#pragma unroll
        for (int ks = 0; ks < 2; ++ks) {
            bf16x8 pa = *(const bf16x8*)&Ps[(w * 16 + l16) * PSTR + ks * 32 + quad * 8];
#pragma unroll
            for (int dt = 0; dt < 8; ++dt) {
                bf16x8 vb = *(const bf16x8*)&Vt[(dt * 16 + l16) * VSTR + ks * 32 + quad * 8];
                acc_o[dt] = __builtin_amdgcn_mfma_f32_16x16x32_bf16(pa, vb, acc_o[dt], 0, 0, 0);
            }
        }
    }

    float linv[4];
#pragma unroll
    for (int reg = 0; reg < 4; ++reg) linv[reg] = 1.f / l_i[reg];
#pragma unroll
    for (int dt = 0; dt < 8; ++dt)
#pragma unroll
        for (int reg = 0; reg < 4; ++reg)
            ctx[(size_t)(b * SS + q0 + w * 16 + quad * 4 + reg) * EE + h * DD + dt * 16 + l16] =
                f2bf(acc_o[dt][reg] * linv[reg]);
}

// ---------------------------------------------------------------------------
extern "C" void kernel_launch(void* const* d_in, const int* in_sizes, int n_in,
                              void* d_out, int out_size, void* d_ws, size_t ws_size,
                              hipStream_t stream) {
    const float* x  = (const float*)d_in[0];
    const float* Wq = (const float*)d_in[1];
    const float* Wk = (const float*)d_in[2];
    const float* Wv = (const float*)d_in[3];
    const float* Wo = (const float*)d_in[4];
    float* out = (float*)d_out;

    const int M = BB * SS;                        // 4096
    u16* xb  = (u16*)d_ws;                        // M*E
    u16* Wqb = xb  + (size_t)M * EE;              // E*E
    u16* Wkb = Wqb + (size_t)EE * EE;             // KVN*E
    u16* Wvb = Wkb + (size_t)KVN * EE;            // KVN*E
    u16* Wob = Wvb + (size_t)KVN * EE;            // E*E
    u16* Qg  = Wob + (size_t)EE * EE;             // M*E
    u16* Kg  = Qg  + (size_t)M * EE;              // M*KVN
    u16* VtG = Kg  + (size_t)M * KVN;             // M*KVN (transposed)
    u16* ctx = VtG + (size_t)M * KVN;             // M*E

    dim3 blk(256);
    cast_bf16<<<dim3((M * EE) / 1024), blk, 0, stream>>>(x, xb, M * EE);
    cast_bf16<<<dim3((EE * EE) / 1024), blk, 0, stream>>>(Wq, Wqb, EE * EE);
    cast_bf16<<<dim3((KVN * EE) / 1024), blk, 0, stream>>>(Wk, Wkb, KVN * EE);
    cast_bf16<<<dim3((KVN * EE) / 1024), blk, 0, stream>>>(Wv, Wvb, KVN * EE);
    cast_bf16<<<dim3((EE * EE) / 1024), blk, 0, stream>>>(Wo, Wob, EE * EE);

    gemm_mfma<1><<<dim3(EE / 128, M / 128), blk, 0, stream>>>(xb, Wqb, Qg, M, EE, EE);
    gemm_mfma<1><<<dim3(KVN / 128, M / 128), blk, 0, stream>>>(xb, Wkb, Kg, M, KVN, EE);
    gemm_mfma<2><<<dim3(KVN / 128, M / 128), blk, 0, stream>>>(xb, Wvb, VtG, M, KVN, EE);
    attn_mfma<<<dim3(SS / 64, HH, BB), blk, 0, stream>>>(Qg, Kg, VtG, ctx);
    gemm_mfma<0><<<dim3(EE / 128, M / 128), blk, 0, stream>>>(ctx, Wob, out, M, EE, EE);
}

// Round 4
// 398.806 us; speedup vs baseline: 9.2463x; 1.2664x over previous
//
#include <hip/hip_runtime.h>
#include <math.h>

#define BB 2
#define SS 2048
#define EE 2048
#define HH 16
#define KVHH 4
#define DD 128
#define GG (HH / KVHH)
#define KVN (KVHH * DD)   // 512
#define SCALE 0.08838834764831843f

typedef __attribute__((ext_vector_type(8))) short bf16x8;
typedef __attribute__((ext_vector_type(4))) float f32x4;
typedef unsigned short u16;
typedef unsigned int u32;

__device__ __forceinline__ u16 f2bf(float f) {
    union { float f; u32 u; } x; x.f = f;
    u32 r = x.u + 0x7fff + ((x.u >> 16) & 1);   // RNE
    return (u16)(r >> 16);
}

__device__ __forceinline__ void gload_lds16(const void* g, void* l) {
    __builtin_amdgcn_global_load_lds(
        (const __attribute__((address_space(1))) u32*)g,
        (__attribute__((address_space(3))) u32*)l, 16, 0, 0);
}

// 16-lane (row-group) reductions via DPP — no LDS-pipe traffic.
__device__ __forceinline__ float dpp_max16(float x) {
    float y;
    y = __int_as_float(__builtin_amdgcn_mov_dpp(__float_as_int(x), 0xB1, 0xF, 0xF, true));  x = fmaxf(x, y);
    y = __int_as_float(__builtin_amdgcn_mov_dpp(__float_as_int(x), 0x4E, 0xF, 0xF, true));  x = fmaxf(x, y);
    y = __int_as_float(__builtin_amdgcn_mov_dpp(__float_as_int(x), 0x141, 0xF, 0xF, true)); x = fmaxf(x, y);
    y = __int_as_float(__builtin_amdgcn_mov_dpp(__float_as_int(x), 0x140, 0xF, 0xF, true)); x = fmaxf(x, y);
    return x;
}
__device__ __forceinline__ float dpp_sum16(float x) {
    float y;
    y = __int_as_float(__builtin_amdgcn_mov_dpp(__float_as_int(x), 0xB1, 0xF, 0xF, true));  x += y;
    y = __int_as_float(__builtin_amdgcn_mov_dpp(__float_as_int(x), 0x4E, 0xF, 0xF, true));  x += y;
    y = __int_as_float(__builtin_amdgcn_mov_dpp(__float_as_int(x), 0x141, 0xF, 0xF, true)); x += y;
    y = __int_as_float(__builtin_amdgcn_mov_dpp(__float_as_int(x), 0x140, 0xF, 0xF, true)); x += y;
    return x;
}

// ---------------------------------------------------------------------------
// Fused fp32->bf16 cast of all 5 tensors. Block-granular segments, 1024 el/blk.
// ---------------------------------------------------------------------------
#define NB_X  8192      // B*S*E / 1024
#define NB_QO 4096      // E*E / 1024
#define NB_KV 1024      // KVN*E / 1024
__global__ __launch_bounds__(256) void cast_all(const float* __restrict__ x,
                                                const float* __restrict__ wq,
                                                const float* __restrict__ wk,
                                                const float* __restrict__ wv,
                                                const float* __restrict__ wo,
                                                u16* __restrict__ xb, u16* __restrict__ wqb,
                                                u16* __restrict__ wkb, u16* __restrict__ wvb,
                                                u16* __restrict__ wob) {
    int bid = blockIdx.x;
    const float* src; u16* dst; int off;
    if (bid < NB_X)                       { src = x;  dst = xb;  off = bid * 1024; }
    else if (bid < NB_X + NB_QO)          { src = wq; dst = wqb; off = (bid - NB_X) * 1024; }
    else if (bid < NB_X + NB_QO + NB_KV)  { src = wk; dst = wkb; off = (bid - NB_X - NB_QO) * 1024; }
    else if (bid < NB_X + NB_QO + 2*NB_KV){ src = wv; dst = wvb; off = (bid - NB_X - NB_QO - NB_KV) * 1024; }
    else                                  { src = wo; dst = wob; off = (bid - NB_X - NB_QO - 2*NB_KV) * 1024; }
    int i = off + threadIdx.x * 4;
    float4 v = *(const float4*)&src[i];
    ushort4 o;
    o.x = f2bf(v.x); o.y = f2bf(v.y); o.z = f2bf(v.z); o.w = f2bf(v.w);
    *(ushort4*)&dst[i] = o;
}

// ---------------------------------------------------------------------------
// m97-structure MFMA GEMM: C[M,N] = A[M,K] @ B[N,K]^T, bf16 in, fp32 acc.
// MODE 0: fp32 row-major C
// MODE 3: bf16 row-major C, scaled by SCALE (Q projection)
// MODE 4: fused KV: n<512 -> Kg row-major [M][512]; n>=512 -> Vt [(b*512+n-512)][S]
// ---------------------------------------------------------------------------
template <int MODE>
__global__ __launch_bounds__(256) void gemm_mfma(const u16* __restrict__ A,
                                                 const u16* __restrict__ B,
                                                 void* __restrict__ Cv,
                                                 void* __restrict__ Cv2,
                                                 int M, int N, int K) {
    __shared__ __align__(16) u16 As[128 * 32];
    __shared__ __align__(16) u16 Bs[128 * 32];
    const int tid  = threadIdx.x;
    const int w    = tid >> 6;
    const int lane = tid & 63;
    const int l16  = lane & 15;
    const int quad = lane >> 4;
    const int wm = (w >> 1) * 64;
    const int wn = (w & 1) * 64;
    const int m0 = blockIdx.y * 128;
    const int n0 = blockIdx.x * 128;

    const int r0 = tid >> 2,           ko0 = (tid & 3) * 8;
    const int r1 = (256 + tid) >> 2,   ko1 = (tid & 3) * 8;
    u16* ldsA0 = &As[(size_t)(w * 64) * 8];
    u16* ldsA1 = &As[(size_t)(256 + w * 64) * 8];
    u16* ldsB0 = &Bs[(size_t)(w * 64) * 8];
    u16* ldsB1 = &Bs[(size_t)(256 + w * 64) * 8];

    f32x4 acc[4][4];
#pragma unroll
    for (int i = 0; i < 4; ++i)
#pragma unroll
        for (int j = 0; j < 4; ++j) acc[i][j] = (f32x4){0.f, 0.f, 0.f, 0.f};

    for (int k0 = 0; k0 < K; k0 += 32) {
        __syncthreads();
        gload_lds16(A + (size_t)(m0 + r0) * K + k0 + ko0, ldsA0);
        gload_lds16(A + (size_t)(m0 + r1) * K + k0 + ko1, ldsA1);
        gload_lds16(B + (size_t)(n0 + r0) * K + k0 + ko0, ldsB0);
        gload_lds16(B + (size_t)(n0 + r1) * K + k0 + ko1, ldsB1);
        __syncthreads();

        bf16x8 af[4], bfr[4];
#pragma unroll
        for (int i = 0; i < 4; ++i)
            af[i] = *(const bf16x8*)&As[(wm + i * 16 + l16) * 32 + quad * 8];
#pragma unroll
        for (int j = 0; j < 4; ++j)
            bfr[j] = *(const bf16x8*)&Bs[(wn + j * 16 + l16) * 32 + quad * 8];
#pragma unroll
        for (int i = 0; i < 4; ++i)
#pragma unroll
            for (int j = 0; j < 4; ++j)
                acc[i][j] = __builtin_amdgcn_mfma_f32_16x16x32_bf16(af[i], bfr[j], acc[i][j], 0, 0, 0);
    }

    if (MODE == 0) {
        float* C = (float*)Cv;
#pragma unroll
        for (int i = 0; i < 4; ++i)
#pragma unroll
            for (int j = 0; j < 4; ++j)
#pragma unroll
                for (int reg = 0; reg < 4; ++reg)
                    C[(size_t)(m0 + wm + i * 16 + quad * 4 + reg) * N + n0 + wn + j * 16 + l16] =
                        acc[i][j][reg];
    } else if (MODE == 3) {
        u16* C = (u16*)Cv;
#pragma unroll
        for (int i = 0; i < 4; ++i)
#pragma unroll
            for (int j = 0; j < 4; ++j)
#pragma unroll
                for (int reg = 0; reg < 4; ++reg)
                    C[(size_t)(m0 + wm + i * 16 + quad * 4 + reg) * N + n0 + wn + j * 16 + l16] =
                        f2bf(acc[i][j][reg] * SCALE);
    } else {   // MODE 4
        if (n0 < 512) {
            u16* C = (u16*)Cv;   // Kg [M][KVN]
#pragma unroll
            for (int i = 0; i < 4; ++i)
#pragma unroll
                for (int j = 0; j < 4; ++j)
#pragma unroll
                    for (int reg = 0; reg < 4; ++reg)
                        C[(size_t)(m0 + wm + i * 16 + quad * 4 + reg) * KVN + n0 + wn + j * 16 + l16] =
                            f2bf(acc[i][j][reg]);
        } else {
            u16* C2 = (u16*)Cv2;  // Vt [(b*KVN + d)][S]
#pragma unroll
            for (int i = 0; i < 4; ++i) {
                const int m = m0 + wm + i * 16 + quad * 4;
                const int bb = m >> 11;
                const int s  = m & (SS - 1);
#pragma unroll
                for (int j = 0; j < 4; ++j) {
                    const int d = n0 + wn + j * 16 + l16 - 512;
                    ushort4 p;
                    p.x = f2bf(acc[i][j][0]); p.y = f2bf(acc[i][j][1]);
                    p.z = f2bf(acc[i][j][2]); p.w = f2bf(acc[i][j][3]);
                    *(ushort4*)&C2[((size_t)(bb * KVN + d)) * SS + s] = p;
                }
            }
        }
    }
}

// ---------------------------------------------------------------------------
// Flash-style causal GQA attention, bf16 MFMA, Q-tile 128 x K-tile 64.
// Qg bf16 [B*S,E] (pre-scaled by SCALE); Kg bf16 [B*S,KVN];
// VtG bf16 [(b*KVN + d)][S]; ctx OUT bf16 [B*S,E].
// 256 threads = 4 waves; wave w owns q-row frags at mi*64 + w*16 (mi=0,1).
// ---------------------------------------------------------------------------
#define KSTR 136
#define VSTR 72
#define PSTR 72

__global__ __launch_bounds__(256, 2) void attn_mfma(const u16* __restrict__ Qg,
                                                    const u16* __restrict__ Kg,
                                                    const u16* __restrict__ VtG,
                                                    u16* __restrict__ ctx) {
    __shared__ __align__(16) u16 Ks[64 * KSTR];    // 17408 B
    __shared__ __align__(16) u16 Vt[128 * VSTR];   // 18432 B
    __shared__ __align__(16) u16 Ps[128 * PSTR];   // 18432 B

    const int tid  = threadIdx.x;
    const int w    = tid >> 6;
    const int lane = tid & 63;
    const int l16  = lane & 15;
    const int quad = lane >> 4;
    const int qc = (int)gridDim.x - 1 - (int)blockIdx.x;  // long blocks first
    const int h  = blockIdx.y;
    const int b  = blockIdx.z;
    const int kvh = h / GG;
    const int q0 = qc * 128;

    // ---- Q fragments direct from global (once per block) ----
    bf16x8 Qa[2][4];
#pragma unroll
    for (int mi = 0; mi < 2; ++mi)
#pragma unroll
        for (int kd = 0; kd < 4; ++kd)
            Qa[mi][kd] = *(const bf16x8*)(Qg + (size_t)(b * SS + q0 + mi * 64 + w * 16 + l16) * EE
                                          + h * DD + kd * 32 + quad * 8);

    float m_i[2][4], l_i[2][4];
#pragma unroll
    for (int mi = 0; mi < 2; ++mi)
#pragma unroll
        for (int r = 0; r < 4; ++r) { m_i[mi][r] = -INFINITY; l_i[mi][r] = 0.f; }
    f32x4 acc_o[2][8];
#pragma unroll
    for (int mi = 0; mi < 2; ++mi)
#pragma unroll
        for (int dt = 0; dt < 8; ++dt) acc_o[mi][dt] = (f32x4){0.f, 0.f, 0.f, 0.f};

    const int ktlast = 2 * qc + 1;

    for (int kt = 0; kt <= ktlast; ++kt) {
        __syncthreads();
        // ---- stage K tile (64 x 128) ----
#pragma unroll
        for (int p = 0; p < 4; ++p) {
            int idx = p * 256 + tid;
            int r  = idx >> 4;
            int c8 = (idx & 15) * 8;
            float4 v = *(const float4*)(Kg + (size_t)(b * SS + kt * 64 + r) * KVN + kvh * DD + c8);
            *(float4*)&Ks[r * KSTR + c8] = v;
        }
        // ---- stage Vt tile (128 d x 64 kk) ----
#pragma unroll
        for (int p = 0; p < 4; ++p) {
            int idx = p * 256 + tid;
            int r  = idx >> 3;
            int c8 = (idx & 7) * 8;
            float4 v = *(const float4*)(VtG + ((size_t)(b * KVN + kvh * DD + r)) * SS + kt * 64 + c8);
            *(float4*)&Vt[r * VSTR + c8] = v;
        }
        __syncthreads();

        const bool skip0 = (kt == ktlast);   // mi=0 rows fully masked on last k-tile

        // ---- QK^T: K-frags loaded once, reused for both mi ----
        f32x4 sc[2][4];
#pragma unroll
        for (int mi = 0; mi < 2; ++mi)
#pragma unroll
            for (int kkt = 0; kkt < 4; ++kkt) sc[mi][kkt] = (f32x4){0.f, 0.f, 0.f, 0.f};
#pragma unroll
        for (int kkt = 0; kkt < 4; ++kkt) {
            bf16x8 kb[4];
#pragma unroll
            for (int kd = 0; kd < 4; ++kd)
                kb[kd] = *(const bf16x8*)&Ks[(kkt * 16 + l16) * KSTR + kd * 32 + quad * 8];
#pragma unroll
            for (int kd = 0; kd < 4; ++kd)
                sc[1][kkt] = __builtin_amdgcn_mfma_f32_16x16x32_bf16(Qa[1][kd], kb[kd], sc[1][kkt], 0, 0, 0);
            if (!skip0)
#pragma unroll
                for (int kd = 0; kd < 4; ++kd)
                    sc[0][kkt] = __builtin_amdgcn_mfma_f32_16x16x32_bf16(Qa[0][kd], kb[kd], sc[0][kkt], 0, 0, 0);
        }

        // ---- online softmax (C layout: q = quad*4+reg offset, k-col = kkt*16+l16) ----
        float alpha[2][4];
#pragma unroll
        for (int mi = 0; mi < 2; ++mi) {
            if (mi == 0 && skip0) continue;
            const bool diag = (kt == 2 * qc + mi);
            const int qrow = q0 + mi * 64 + w * 16 + quad * 4;
            const int kbase = kt * 64 + l16;
#pragma unroll
            for (int reg = 0; reg < 4; ++reg) {
                float rowmax = -INFINITY;
#pragma unroll
                for (int kkt = 0; kkt < 4; ++kkt) {
                    float v = sc[mi][kkt][reg];
                    if (diag && (kbase + kkt * 16 > qrow + reg)) v = -INFINITY;
                    sc[mi][kkt][reg] = v;
                    rowmax = fmaxf(rowmax, v);
                }
                rowmax = dpp_max16(rowmax);
                float mnew = fmaxf(m_i[mi][reg], rowmax);
                float rsum = 0.f;
#pragma unroll
                for (int kkt = 0; kkt < 4; ++kkt) {
                    float p = __expf(sc[mi][kkt][reg] - mnew);
                    sc[mi][kkt][reg] = p;
                    rsum += p;
                }
                rsum = dpp_sum16(rsum);
                alpha[mi][reg] = __expf(m_i[mi][reg] - mnew);
                l_i[mi][reg] = l_i[mi][reg] * alpha[mi][reg] + rsum;
                m_i[mi][reg] = mnew;
#pragma unroll
                for (int kkt = 0; kkt < 4; ++kkt)
                    Ps[(mi * 64 + w * 16 + quad * 4 + reg) * PSTR + kkt * 16 + l16] =
                        f2bf(sc[mi][kkt][reg]);
            }
        }
        __syncthreads();

        // ---- rescale O ----
#pragma unroll
        for (int mi = 0; mi < 2; ++mi) {
            if (mi == 0 && skip0) continue;
#pragma unroll
            for (int dt = 0; dt < 8; ++dt)
#pragma unroll
                for (int reg = 0; reg < 4; ++reg)
                    acc_o[mi][dt][reg] *= alpha[mi][reg];
        }

        // ---- O += P V : V-frags loaded once, reused for both mi ----
#pragma unroll
        for (int ks = 0; ks < 2; ++ks) {
            bf16x8 pa1 = *(const bf16x8*)&Ps[(64 + w * 16 + l16) * PSTR + ks * 32 + quad * 8];
            bf16x8 pa0;
            if (!skip0) pa0 = *(const bf16x8*)&Ps[(w * 16 + l16) * PSTR + ks * 32 + quad * 8];
#pragma unroll
            for (int dt = 0; dt < 8; ++dt) {
                bf16x8 vb = *(const bf16x8*)&Vt[(dt * 16 + l16) * VSTR + ks * 32 + quad * 8];
                acc_o[1][dt] = __builtin_amdgcn_mfma_f32_16x16x32_bf16(pa1, vb, acc_o[1][dt], 0, 0, 0);
                if (!skip0)
                    acc_o[0][dt] = __builtin_amdgcn_mfma_f32_16x16x32_bf16(pa0, vb, acc_o[0][dt], 0, 0, 0);
            }
        }
    }

    // ---- epilogue ----
#pragma unroll
    for (int mi = 0; mi < 2; ++mi) {
        float linv[4];
#pragma unroll
        for (int reg = 0; reg < 4; ++reg) linv[reg] = 1.f / l_i[mi][reg];
#pragma unroll
        for (int dt = 0; dt < 8; ++dt)
#pragma unroll
            for (int reg = 0; reg < 4; ++reg)
                ctx[(size_t)(b * SS + q0 + mi * 64 + w * 16 + quad * 4 + reg) * EE
                    + h * DD + dt * 16 + l16] = f2bf(acc_o[mi][dt][reg] * linv[reg]);
    }
}

// ---------------------------------------------------------------------------
extern "C" void kernel_launch(void* const* d_in, const int* in_sizes, int n_in,
                              void* d_out, int out_size, void* d_ws, size_t ws_size,
                              hipStream_t stream) {
    const float* x  = (const float*)d_in[0];
    const float* Wq = (const float*)d_in[1];
    const float* Wk = (const float*)d_in[2];
    const float* Wv = (const float*)d_in[3];
    const float* Wo = (const float*)d_in[4];
    float* out = (float*)d_out;

    const int M = BB * SS;                        // 4096
    u16* xb  = (u16*)d_ws;                        // M*E
    u16* Wqb = xb  + (size_t)M * EE;              // E*E
    u16* Wkb = Wqb + (size_t)EE * EE;             // KVN*E  (Wvb contiguous after!)
    u16* Wvb = Wkb + (size_t)KVN * EE;            // KVN*E
    u16* Wob = Wvb + (size_t)KVN * EE;            // E*E
    u16* Qg  = Wob + (size_t)EE * EE;             // M*E
    u16* Kg  = Qg  + (size_t)M * EE;              // M*KVN
    u16* VtG = Kg  + (size_t)M * KVN;             // M*KVN (transposed)
    u16* ctx = VtG + (size_t)M * KVN;             // M*E

    dim3 blk(256);
    cast_all<<<dim3(NB_X + NB_QO + 2 * NB_KV + NB_QO), blk, 0, stream>>>(
        x, Wq, Wk, Wv, Wo, xb, Wqb, Wkb, Wvb, Wob);

    gemm_mfma<3><<<dim3(EE / 128, M / 128), blk, 0, stream>>>(xb, Wqb, Qg, nullptr, M, EE, EE);
    gemm_mfma<4><<<dim3((2 * KVN) / 128, M / 128), blk, 0, stream>>>(xb, Wkb, Kg, VtG, M, 2 * KVN, EE);
    attn_mfma<<<dim3(SS / 128, HH, BB), blk, 0, stream>>>(Qg, Kg, VtG, ctx);
    gemm_mfma<0><<<dim3(EE / 128, M / 128), blk, 0, stream>>>(ctx, Wob, out, nullptr, M, EE, EE);
}

// Round 5
// 342.638 us; speedup vs baseline: 10.7620x; 1.1639x over previous
//
#include <hip/hip_runtime.h>
#include <math.h>

#define BB 2
#define SS 2048
#define EE 2048
#define HH 16
#define KVHH 4
#define DD 128
#define GG (HH / KVHH)
#define KVN (KVHH * DD)   // 512
#define SCALE 0.08838834764831843f

typedef __attribute__((ext_vector_type(8))) short bf16x8;
typedef __attribute__((ext_vector_type(4))) float f32x4;
typedef unsigned short u16;
typedef unsigned int u32;

__device__ __forceinline__ u16 f2bf(float f) {
    union { float f; u32 u; } x; x.f = f;
    u32 r = x.u + 0x7fff + ((x.u >> 16) & 1);   // RNE
    return (u16)(r >> 16);
}
__device__ __forceinline__ u32 f2bf_pk(float a, float b) {
    return (u32)f2bf(a) | ((u32)f2bf(b) << 16);
}

__device__ __forceinline__ void gload_lds16(const void* g, void* l) {
    __builtin_amdgcn_global_load_lds(
        (const __attribute__((address_space(1))) u32*)g,
        (__attribute__((address_space(3))) u32*)l, 16, 0, 0);
}

// ---------------------------------------------------------------------------
// Fused fp32->bf16 cast of all 5 tensors. Block-granular segments, 1024 el/blk.
// ---------------------------------------------------------------------------
#define NB_X  8192      // B*S*E / 1024
#define NB_QO 4096      // E*E / 1024
#define NB_KV 1024      // KVN*E / 1024
__global__ __launch_bounds__(256) void cast_all(const float* __restrict__ x,
                                                const float* __restrict__ wq,
                                                const float* __restrict__ wk,
                                                const float* __restrict__ wv,
                                                const float* __restrict__ wo,
                                                u16* __restrict__ xb, u16* __restrict__ wqb,
                                                u16* __restrict__ wkb, u16* __restrict__ wvb,
                                                u16* __restrict__ wob) {
    int bid = blockIdx.x;
    const float* src; u16* dst; int off;
    if (bid < NB_X)                       { src = x;  dst = xb;  off = bid * 1024; }
    else if (bid < NB_X + NB_QO)          { src = wq; dst = wqb; off = (bid - NB_X) * 1024; }
    else if (bid < NB_X + NB_QO + NB_KV)  { src = wk; dst = wkb; off = (bid - NB_X - NB_QO) * 1024; }
    else if (bid < NB_X + NB_QO + 2*NB_KV){ src = wv; dst = wvb; off = (bid - NB_X - NB_QO - NB_KV) * 1024; }
    else                                  { src = wo; dst = wob; off = (bid - NB_X - NB_QO - 2*NB_KV) * 1024; }
    int i = off + threadIdx.x * 4;
    float4 v = *(const float4*)&src[i];
    ushort4 o;
    o.x = f2bf(v.x); o.y = f2bf(v.y); o.z = f2bf(v.z); o.w = f2bf(v.w);
    *(ushort4*)&dst[i] = o;
}

// ---------------------------------------------------------------------------
// m97-structure MFMA GEMM: C[M,N] = A[M,K] @ B[N,K]^T, bf16 in, fp32 acc.
// MODE 0: fp32 row-major C
// MODE 3: bf16 row-major C, scaled by SCALE (Q projection)
// MODE 4: fused KV: n<512 -> Kg row-major [M][512]; n>=512 -> Vt [(b*512+n-512)][S]
// ---------------------------------------------------------------------------
template <int MODE>
__global__ __launch_bounds__(256) void gemm_mfma(const u16* __restrict__ A,
                                                 const u16* __restrict__ B,
                                                 void* __restrict__ Cv,
                                                 void* __restrict__ Cv2,
                                                 int M, int N, int K) {
    __shared__ __align__(16) u16 As[128 * 32];
    __shared__ __align__(16) u16 Bs[128 * 32];
    const int tid  = threadIdx.x;
    const int w    = tid >> 6;
    const int lane = tid & 63;
    const int l16  = lane & 15;
    const int quad = lane >> 4;
    const int wm = (w >> 1) * 64;
    const int wn = (w & 1) * 64;
    const int m0 = blockIdx.y * 128;
    const int n0 = blockIdx.x * 128;

    const int r0 = tid >> 2,           ko0 = (tid & 3) * 8;
    const int r1 = (256 + tid) >> 2,   ko1 = (tid & 3) * 8;
    u16* ldsA0 = &As[(size_t)(w * 64) * 8];
    u16* ldsA1 = &As[(size_t)(256 + w * 64) * 8];
    u16* ldsB0 = &Bs[(size_t)(w * 64) * 8];
    u16* ldsB1 = &Bs[(size_t)(256 + w * 64) * 8];

    f32x4 acc[4][4];
#pragma unroll
    for (int i = 0; i < 4; ++i)
#pragma unroll
        for (int j = 0; j < 4; ++j) acc[i][j] = (f32x4){0.f, 0.f, 0.f, 0.f};

    for (int k0 = 0; k0 < K; k0 += 32) {
        __syncthreads();
        gload_lds16(A + (size_t)(m0 + r0) * K + k0 + ko0, ldsA0);
        gload_lds16(A + (size_t)(m0 + r1) * K + k0 + ko1, ldsA1);
        gload_lds16(B + (size_t)(n0 + r0) * K + k0 + ko0, ldsB0);
        gload_lds16(B + (size_t)(n0 + r1) * K + k0 + ko1, ldsB1);
        __syncthreads();

        bf16x8 af[4], bfr[4];
#pragma unroll
        for (int i = 0; i < 4; ++i)
            af[i] = *(const bf16x8*)&As[(wm + i * 16 + l16) * 32 + quad * 8];
#pragma unroll
        for (int j = 0; j < 4; ++j)
            bfr[j] = *(const bf16x8*)&Bs[(wn + j * 16 + l16) * 32 + quad * 8];
#pragma unroll
        for (int i = 0; i < 4; ++i)
#pragma unroll
            for (int j = 0; j < 4; ++j)
                acc[i][j] = __builtin_amdgcn_mfma_f32_16x16x32_bf16(af[i], bfr[j], acc[i][j], 0, 0, 0);
    }

    if (MODE == 0) {
        float* C = (float*)Cv;
#pragma unroll
        for (int i = 0; i < 4; ++i)
#pragma unroll
            for (int j = 0; j < 4; ++j)
#pragma unroll
                for (int reg = 0; reg < 4; ++reg)
                    C[(size_t)(m0 + wm + i * 16 + quad * 4 + reg) * N + n0 + wn + j * 16 + l16] =
                        acc[i][j][reg];
    } else if (MODE == 3) {
        u16* C = (u16*)Cv;
#pragma unroll
        for (int i = 0; i < 4; ++i)
#pragma unroll
            for (int j = 0; j < 4; ++j)
#pragma unroll
                for (int reg = 0; reg < 4; ++reg)
                    C[(size_t)(m0 + wm + i * 16 + quad * 4 + reg) * N + n0 + wn + j * 16 + l16] =
                        f2bf(acc[i][j][reg] * SCALE);
    } else {   // MODE 4
        if (n0 < 512) {
            u16* C = (u16*)Cv;   // Kg [M][KVN]
#pragma unroll
            for (int i = 0; i < 4; ++i)
#pragma unroll
                for (int j = 0; j < 4; ++j)
#pragma unroll
                    for (int reg = 0; reg < 4; ++reg)
                        C[(size_t)(m0 + wm + i * 16 + quad * 4 + reg) * KVN + n0 + wn + j * 16 + l16] =
                            f2bf(acc[i][j][reg]);
        } else {
            u16* C2 = (u16*)Cv2;  // Vt [(b*KVN + d)][S]
#pragma unroll
            for (int i = 0; i < 4; ++i) {
                const int m = m0 + wm + i * 16 + quad * 4;
                const int bb = m >> 11;
                const int s  = m & (SS - 1);
#pragma unroll
                for (int j = 0; j < 4; ++j) {
                    const int d = n0 + wn + j * 16 + l16 - 512;
                    ushort4 p;
                    p.x = f2bf(acc[i][j][0]); p.y = f2bf(acc[i][j][1]);
                    p.z = f2bf(acc[i][j][2]); p.w = f2bf(acc[i][j][3]);
                    *(ushort4*)&C2[((size_t)(bb * KVN + d)) * SS + s] = p;
                }
            }
        }
    }
}

// ---------------------------------------------------------------------------
// Flash-style causal GQA attention, bf16 MFMA, Q-tile 128 x K-tile 64.
// Transposed-score formulation:
//   S^T = mfma(A=K-frag, B=Q-frag)  -> lane holds q=l16 col, k rows in regs
//   O^T = mfma(A=Vt-frag, B=P^T-frag from LDS)
// Per-lane softmax state (q = l16, replicated across quads). P-writes are
// packed b64 and wave-local (no barrier between softmax and PV).
// Grid: flat 512 blocks; qc mapping pairs complementary chunks on one CU.
// ---------------------------------------------------------------------------
#define KSTR 136
#define VSTR 72
#define PSTR 72

__global__ __launch_bounds__(256, 2) void attn_mfma(const u16* __restrict__ Qg,
                                                    const u16* __restrict__ Kg,
                                                    const u16* __restrict__ VtG,
                                                    u16* __restrict__ ctx) {
    __shared__ __align__(16) u16 Ks[64 * KSTR];    // 17408 B
    __shared__ __align__(16) u16 Vt[128 * VSTR];   // 18432 B
    __shared__ __align__(16) u16 Ps[128 * PSTR];   // 18432 B

    const int tid  = threadIdx.x;
    const int w    = tid >> 6;
    const int lane = tid & 63;
    const int l16  = lane & 15;
    const int quad = lane >> 4;

    // balanced task map: blocks f and f+256 get qc summing to 15
    const int f    = blockIdx.x;
    const int half = f >> 8;
    const int u    = f & 255;
    const int h    = u & 15;
    const int w2   = u >> 4;
    const int b    = w2 & 1;
    const int j    = w2 >> 1;                  // 0..7
    const int qc   = half ? (15 - j) : j;      // 0..15
    const int kvh  = h / GG;
    const int q0   = qc * 128;

    // ---- Q fragments direct from global (B-operand layout == A layout) ----
    bf16x8 Qa[2][4];
#pragma unroll
    for (int mi = 0; mi < 2; ++mi)
#pragma unroll
        for (int kd = 0; kd < 4; ++kd)
            Qa[mi][kd] = *(const bf16x8*)(Qg + (size_t)(b * SS + q0 + mi * 64 + w * 16 + l16) * EE
                                          + h * DD + kd * 32 + quad * 8);

    float m_i[2], l_i[2];
#pragma unroll
    for (int mi = 0; mi < 2; ++mi) { m_i[mi] = -INFINITY; l_i[mi] = 0.f; }
    f32x4 acc_o[2][8];   // O^T: rows d = dt*16+quad*4+reg, col q = l16
#pragma unroll
    for (int mi = 0; mi < 2; ++mi)
#pragma unroll
        for (int dt = 0; dt < 8; ++dt) acc_o[mi][dt] = (f32x4){0.f, 0.f, 0.f, 0.f};

    const int ktlast = 2 * qc + 1;
    const int myq[2] = { q0 + w * 16 + l16, q0 + 64 + w * 16 + l16 };

    for (int kt = 0; kt <= ktlast; ++kt) {
        __syncthreads();
        // ---- stage K tile (64 x 128) ----
#pragma unroll
        for (int p = 0; p < 4; ++p) {
            int idx = p * 256 + tid;
            int r  = idx >> 4;
            int c8 = (idx & 15) * 8;
            float4 v = *(const float4*)(Kg + (size_t)(b * SS + kt * 64 + r) * KVN + kvh * DD + c8);
            *(float4*)&Ks[r * KSTR + c8] = v;
        }
        // ---- stage Vt tile (128 d x 64 kk) ----
#pragma unroll
        for (int p = 0; p < 4; ++p) {
            int idx = p * 256 + tid;
            int r  = idx >> 3;
            int c8 = (idx & 7) * 8;
            float4 v = *(const float4*)(VtG + ((size_t)(b * KVN + kvh * DD + r)) * SS + kt * 64 + c8);
            *(float4*)&Vt[r * VSTR + c8] = v;
        }
        __syncthreads();

        const bool skip0 = (kt == ktlast);   // mi=0 rows fully masked on last k-tile

        // ---- S^T = K Q^T : lane q=l16, k = kt*64 + kkt*16 + quad*4 + reg ----
        f32x4 sc[2][4];
#pragma unroll
        for (int mi = 0; mi < 2; ++mi)
#pragma unroll
            for (int kkt = 0; kkt < 4; ++kkt) sc[mi][kkt] = (f32x4){0.f, 0.f, 0.f, 0.f};
#pragma unroll
        for (int kkt = 0; kkt < 4; ++kkt) {
            bf16x8 kb[4];
#pragma unroll
            for (int kd = 0; kd < 4; ++kd)
                kb[kd] = *(const bf16x8*)&Ks[(kkt * 16 + l16) * KSTR + kd * 32 + quad * 8];
#pragma unroll
            for (int kd = 0; kd < 4; ++kd)
                sc[1][kkt] = __builtin_amdgcn_mfma_f32_16x16x32_bf16(kb[kd], Qa[1][kd], sc[1][kkt], 0, 0, 0);
            if (!skip0)
#pragma unroll
                for (int kd = 0; kd < 4; ++kd)
                    sc[0][kkt] = __builtin_amdgcn_mfma_f32_16x16x32_bf16(kb[kd], Qa[0][kd], sc[0][kkt], 0, 0, 0);
        }

        // ---- per-lane online softmax ----
        float alpha[2];
#pragma unroll
        for (int mi = 0; mi < 2; ++mi) {
            if (mi == 0 && skip0) { alpha[0] = 1.f; continue; }
            const bool diag = (kt == 2 * qc + mi);
            if (diag) {
                const int kb0 = kt * 64 + quad * 4;
#pragma unroll
                for (int kkt = 0; kkt < 4; ++kkt)
#pragma unroll
                    for (int reg = 0; reg < 4; ++reg)
                        if (kb0 + kkt * 16 + reg > myq[mi]) sc[mi][kkt][reg] = -INFINITY;
            }
            float rowmax = -INFINITY;
#pragma unroll
            for (int kkt = 0; kkt < 4; ++kkt)
#pragma unroll
                for (int reg = 0; reg < 4; ++reg)
                    rowmax = fmaxf(rowmax, sc[mi][kkt][reg]);
            rowmax = fmaxf(rowmax, __shfl_xor(rowmax, 16, 64));
            rowmax = fmaxf(rowmax, __shfl_xor(rowmax, 32, 64));
            float mnew = fmaxf(m_i[mi], rowmax);
            float rsum = 0.f;
#pragma unroll
            for (int kkt = 0; kkt < 4; ++kkt)
#pragma unroll
                for (int reg = 0; reg < 4; ++reg) {
                    float p = __expf(sc[mi][kkt][reg] - mnew);
                    sc[mi][kkt][reg] = p;
                    rsum += p;
                }
            rsum += __shfl_xor(rsum, 16, 64);
            rsum += __shfl_xor(rsum, 32, 64);
            alpha[mi] = __expf(m_i[mi] - mnew);
            l_i[mi] = l_i[mi] * alpha[mi] + rsum;
            m_i[mi] = mnew;
            // packed P^T write: row q, cols k (wave-local rows)
            const int prow = (mi * 64 + w * 16 + l16) * PSTR;
#pragma unroll
            for (int kkt = 0; kkt < 4; ++kkt) {
                uint2 pk;
                pk.x = f2bf_pk(sc[mi][kkt][0], sc[mi][kkt][1]);
                pk.y = f2bf_pk(sc[mi][kkt][2], sc[mi][kkt][3]);
                *(uint2*)&Ps[prow + kkt * 16 + quad * 4] = pk;
            }
        }
        // no barrier: each wave reads only its own Ps rows (lgkmcnt orders it)

        // ---- rescale O ----
#pragma unroll
        for (int mi = 0; mi < 2; ++mi) {
            if (mi == 0 && skip0) continue;
#pragma unroll
            for (int dt = 0; dt < 8; ++dt)
#pragma unroll
                for (int reg = 0; reg < 4; ++reg)
                    acc_o[mi][dt][reg] *= alpha[mi];
        }

        // ---- O^T += V^T P^T ----
#pragma unroll
        for (int ks = 0; ks < 2; ++ks) {
            bf16x8 pb1 = *(const bf16x8*)&Ps[(64 + w * 16 + l16) * PSTR + ks * 32 + quad * 8];
            bf16x8 pb0;
            if (!skip0) pb0 = *(const bf16x8*)&Ps[(w * 16 + l16) * PSTR + ks * 32 + quad * 8];
#pragma unroll
            for (int dt = 0; dt < 8; ++dt) {
                bf16x8 va = *(const bf16x8*)&Vt[(dt * 16 + l16) * VSTR + ks * 32 + quad * 8];
                acc_o[1][dt] = __builtin_amdgcn_mfma_f32_16x16x32_bf16(va, pb1, acc_o[1][dt], 0, 0, 0);
                if (!skip0)
                    acc_o[0][dt] = __builtin_amdgcn_mfma_f32_16x16x32_bf16(va, pb0, acc_o[0][dt], 0, 0, 0);
            }
        }
    }

    // ---- epilogue: packed ushort4 stores, lane q=l16, d=dt*16+quad*4+reg ----
#pragma unroll
    for (int mi = 0; mi < 2; ++mi) {
        const float linv = 1.f / l_i[mi];
        u16* dst = ctx + (size_t)(b * SS + myq[mi]) * EE + h * DD;
#pragma unroll
        for (int dt = 0; dt < 8; ++dt) {
            ushort4 o;
            o.x = f2bf(acc_o[mi][dt][0] * linv);
            o.y = f2bf(acc_o[mi][dt][1] * linv);
            o.z = f2bf(acc_o[mi][dt][2] * linv);
            o.w = f2bf(acc_o[mi][dt][3] * linv);
            *(ushort4*)&dst[dt * 16 + quad * 4] = o;
        }
    }
}

// ---------------------------------------------------------------------------
extern "C" void kernel_launch(void* const* d_in, const int* in_sizes, int n_in,
                              void* d_out, int out_size, void* d_ws, size_t ws_size,
                              hipStream_t stream) {
    const float* x  = (const float*)d_in[0];
    const float* Wq = (const float*)d_in[1];
    const float* Wk = (const float*)d_in[2];
    const float* Wv = (const float*)d_in[3];
    const float* Wo = (const float*)d_in[4];
    float* out = (float*)d_out;

    const int M = BB * SS;                        // 4096
    u16* xb  = (u16*)d_ws;                        // M*E
    u16* Wqb = xb  + (size_t)M * EE;              // E*E
    u16* Wkb = Wqb + (size_t)EE * EE;             // KVN*E  (Wvb contiguous after!)
    u16* Wvb = Wkb + (size_t)KVN * EE;            // KVN*E
    u16* Wob = Wvb + (size_t)KVN * EE;            // E*E
    u16* Qg  = Wob + (size_t)EE * EE;             // M*E
    u16* Kg  = Qg  + (size_t)M * EE;              // M*KVN
    u16* VtG = Kg  + (size_t)M * KVN;             // M*KVN (transposed)
    u16* ctx = VtG + (size_t)M * KVN;             // M*E

    dim3 blk(256);
    cast_all<<<dim3(NB_X + NB_QO + 2 * NB_KV + NB_QO), blk, 0, stream>>>(
        x, Wq, Wk, Wv, Wo, xb, Wqb, Wkb, Wvb, Wob);

    gemm_mfma<3><<<dim3(EE / 128, M / 128), blk, 0, stream>>>(xb, Wqb, Qg, nullptr, M, EE, EE);
    gemm_mfma<4><<<dim3((2 * KVN) / 128, M / 128), blk, 0, stream>>>(xb, Wkb, Kg, VtG, M, 2 * KVN, EE);
    attn_mfma<<<dim3(512), blk, 0, stream>>>(Qg, Kg, VtG, ctx);
    gemm_mfma<0><<<dim3(EE / 128, M / 128), blk, 0, stream>>>(ctx, Wob, out, nullptr, M, EE, EE);
}

// Round 6
// 321.787 us; speedup vs baseline: 11.4594x; 1.0648x over previous
//
#include <hip/hip_runtime.h>
#include <math.h>

#define BB 2
#define SS 2048
#define EE 2048
#define HH 16
#define KVHH 4
#define DD 128
#define GG (HH / KVHH)
#define KVN (KVHH * DD)   // 512
#define SCALE 0.08838834764831843f
// SCALE * log2(e): scores land in log2 domain -> exp2f softmax
#define QSCALE (0.08838834764831843f * 1.4426950408889634f)

typedef __attribute__((ext_vector_type(8))) short bf16x8;
typedef __attribute__((ext_vector_type(4))) float f32x4;
typedef unsigned short u16;
typedef unsigned int u32;

__device__ __forceinline__ u16 f2bf(float f) {
    union { float f; u32 u; } x; x.f = f;
    u32 r = x.u + 0x7fff + ((x.u >> 16) & 1);   // RNE
    return (u16)(r >> 16);
}
__device__ __forceinline__ u32 f2bf_pk(float a, float b) {
    return (u32)f2bf(a) | ((u32)f2bf(b) << 16);
}

__device__ __forceinline__ void gload_lds16(const void* g, void* l) {
    __builtin_amdgcn_global_load_lds(
        (const __attribute__((address_space(1))) u32*)g,
        (__attribute__((address_space(3))) u32*)l, 16, 0, 0);
}

// ---------------------------------------------------------------------------
// Fused fp32->bf16 cast of all 5 tensors. Block-granular segments, 1024 el/blk.
// ---------------------------------------------------------------------------
#define NB_X  8192      // B*S*E / 1024
#define NB_QO 4096      // E*E / 1024
#define NB_KV 1024      // KVN*E / 1024
__global__ __launch_bounds__(256) void cast_all(const float* __restrict__ x,
                                                const float* __restrict__ wq,
                                                const float* __restrict__ wk,
                                                const float* __restrict__ wv,
                                                const float* __restrict__ wo,
                                                u16* __restrict__ xb, u16* __restrict__ wqb,
                                                u16* __restrict__ wkb, u16* __restrict__ wvb,
                                                u16* __restrict__ wob) {
    int bid = blockIdx.x;
    const float* src; u16* dst; int off;
    if (bid < NB_X)                       { src = x;  dst = xb;  off = bid * 1024; }
    else if (bid < NB_X + NB_QO)          { src = wq; dst = wqb; off = (bid - NB_X) * 1024; }
    else if (bid < NB_X + NB_QO + NB_KV)  { src = wk; dst = wkb; off = (bid - NB_X - NB_QO) * 1024; }
    else if (bid < NB_X + NB_QO + 2*NB_KV){ src = wv; dst = wvb; off = (bid - NB_X - NB_QO - NB_KV) * 1024; }
    else                                  { src = wo; dst = wob; off = (bid - NB_X - NB_QO - 2*NB_KV) * 1024; }
    int i = off + threadIdx.x * 4;
    float4 v = *(const float4*)&src[i];
    ushort4 o;
    o.x = f2bf(v.x); o.y = f2bf(v.y); o.z = f2bf(v.z); o.w = f2bf(v.w);
    *(ushort4*)&dst[i] = o;
}

// ---------------------------------------------------------------------------
// m97-structure MFMA GEMM: C[M,N] = A[M,K] @ B[N,K]^T, bf16 in, fp32 acc.
// MODE 0: fp32 row-major C
// MODE 5: fused QKV epilogue (B = [Wq;Wk;Wv] concat, N=3072):
//   n<2048      -> Qg bf16 [M][2048], scaled by QSCALE
//   2048..2559  -> Kg bf16 [M][512]
//   2560..3071  -> Vt bf16 [(b*KVN + d)][S]
// ---------------------------------------------------------------------------
template <int MODE>
__global__ __launch_bounds__(256) void gemm_mfma(const u16* __restrict__ A,
                                                 const u16* __restrict__ B,
                                                 void* __restrict__ Cv,
                                                 void* __restrict__ Cv2,
                                                 void* __restrict__ Cv3,
                                                 int M, int N, int K) {
    __shared__ __align__(16) u16 As[128 * 32];
    __shared__ __align__(16) u16 Bs[128 * 32];
    const int tid  = threadIdx.x;
    const int w    = tid >> 6;
    const int lane = tid & 63;
    const int l16  = lane & 15;
    const int quad = lane >> 4;
    const int wm = (w >> 1) * 64;
    const int wn = (w & 1) * 64;
    const int m0 = blockIdx.y * 128;
    const int n0 = blockIdx.x * 128;

    const int r0 = tid >> 2,           ko0 = (tid & 3) * 8;
    const int r1 = (256 + tid) >> 2,   ko1 = (tid & 3) * 8;
    u16* ldsA0 = &As[(size_t)(w * 64) * 8];
    u16* ldsA1 = &As[(size_t)(256 + w * 64) * 8];
    u16* ldsB0 = &Bs[(size_t)(w * 64) * 8];
    u16* ldsB1 = &Bs[(size_t)(256 + w * 64) * 8];

    f32x4 acc[4][4];
#pragma unroll
    for (int i = 0; i < 4; ++i)
#pragma unroll
        for (int j = 0; j < 4; ++j) acc[i][j] = (f32x4){0.f, 0.f, 0.f, 0.f};

    for (int k0 = 0; k0 < K; k0 += 32) {
        __syncthreads();
        gload_lds16(A + (size_t)(m0 + r0) * K + k0 + ko0, ldsA0);
        gload_lds16(A + (size_t)(m0 + r1) * K + k0 + ko1, ldsA1);
        gload_lds16(B + (size_t)(n0 + r0) * K + k0 + ko0, ldsB0);
        gload_lds16(B + (size_t)(n0 + r1) * K + k0 + ko1, ldsB1);
        __syncthreads();

        bf16x8 af[4], bfr[4];
#pragma unroll
        for (int i = 0; i < 4; ++i)
            af[i] = *(const bf16x8*)&As[(wm + i * 16 + l16) * 32 + quad * 8];
#pragma unroll
        for (int j = 0; j < 4; ++j)
            bfr[j] = *(const bf16x8*)&Bs[(wn + j * 16 + l16) * 32 + quad * 8];
#pragma unroll
        for (int i = 0; i < 4; ++i)
#pragma unroll
            for (int j = 0; j < 4; ++j)
                acc[i][j] = __builtin_amdgcn_mfma_f32_16x16x32_bf16(af[i], bfr[j], acc[i][j], 0, 0, 0);
    }

    if (MODE == 0) {
        float* C = (float*)Cv;
#pragma unroll
        for (int i = 0; i < 4; ++i)
#pragma unroll
            for (int j = 0; j < 4; ++j)
#pragma unroll
                for (int reg = 0; reg < 4; ++reg)
                    C[(size_t)(m0 + wm + i * 16 + quad * 4 + reg) * N + n0 + wn + j * 16 + l16] =
                        acc[i][j][reg];
    } else {   // MODE 5
        if (n0 < 2048) {
            u16* C = (u16*)Cv;   // Qg [M][2048], QSCALE folded in
#pragma unroll
            for (int i = 0; i < 4; ++i)
#pragma unroll
                for (int j = 0; j < 4; ++j)
#pragma unroll
                    for (int reg = 0; reg < 4; ++reg)
                        C[(size_t)(m0 + wm + i * 16 + quad * 4 + reg) * 2048 + n0 + wn + j * 16 + l16] =
                            f2bf(acc[i][j][reg] * QSCALE);
        } else if (n0 < 2560) {
            u16* C = (u16*)Cv2;  // Kg [M][512]
            const int nb = n0 - 2048;
#pragma unroll
            for (int i = 0; i < 4; ++i)
#pragma unroll
                for (int j = 0; j < 4; ++j)
#pragma unroll
                    for (int reg = 0; reg < 4; ++reg)
                        C[(size_t)(m0 + wm + i * 16 + quad * 4 + reg) * KVN + nb + wn + j * 16 + l16] =
                            f2bf(acc[i][j][reg]);
        } else {
            u16* C2 = (u16*)Cv3;  // Vt [(b*KVN + d)][S]
            const int db = n0 - 2560;
#pragma unroll
            for (int i = 0; i < 4; ++i) {
                const int m = m0 + wm + i * 16 + quad * 4;
                const int bb = m >> 11;
                const int s  = m & (SS - 1);
#pragma unroll
                for (int j = 0; j < 4; ++j) {
                    const int d = db + wn + j * 16 + l16;
                    ushort4 p;
                    p.x = f2bf(acc[i][j][0]); p.y = f2bf(acc[i][j][1]);
                    p.z = f2bf(acc[i][j][2]); p.w = f2bf(acc[i][j][3]);
                    *(ushort4*)&C2[((size_t)(bb * KVN + d)) * SS + s] = p;
                }
            }
        }
    }
}

// ---------------------------------------------------------------------------
// Flash-style causal GQA attention, bf16 MFMA, Q-tile 128 x K-tile 64.
// Transposed-score formulation (S^T / O^T) with per-lane softmax state.
// K/V staged via global_load_lds into XOR-swizzled unpadded LDS, double-
// buffered: DMA for tile kt+1 issued right after the barrier, overlapping
// the whole compute phase of tile kt. P swizzled the same way (16-B chunks,
// chunk c stored at c ^ (row & 7)) -> all LDS access <=2-way (free).
// LDS = 32 (Kdbuf) + 32 (Vdbuf) + 16 (P) = 80 KB -> 2 blocks/CU.
// ---------------------------------------------------------------------------
__global__ __launch_bounds__(256, 2) void attn_mfma(const u16* __restrict__ Qg,
                                                    const u16* __restrict__ Kg,
                                                    const u16* __restrict__ VtG,
                                                    u16* __restrict__ ctx) {
    __shared__ __align__(16) u16 Ks[2][64 * 128];    // 2 x 16 KB
    __shared__ __align__(16) u16 Vt[2][128 * 64];    // 2 x 16 KB
    __shared__ __align__(16) u16 Ps[128 * 64];       // 16 KB

    const int tid  = threadIdx.x;
    const int w    = tid >> 6;
    const int lane = tid & 63;
    const int l16  = lane & 15;
    const int quad = lane >> 4;
    const int sw   = l16 & 7;            // swizzle key for all fragment rows

    // balanced task map: blocks f and f+256 get qc summing to 15
    const int f    = blockIdx.x;
    const int half = f >> 8;
    const int u    = f & 255;
    const int h    = u & 15;
    const int w2   = u >> 4;
    const int b    = w2 & 1;
    const int j    = w2 >> 1;                  // 0..7
    const int qc   = half ? (15 - j) : j;      // 0..15
    const int kvh  = h / GG;
    const int q0   = qc * 128;

    const size_t kgbase = (size_t)(b * SS) * KVN + kvh * DD;
    const size_t vgbase = (size_t)(b * KVN + kvh * DD) * SS;

    // ---- Q fragments direct from global ----
    bf16x8 Qa[2][4];
#pragma unroll
    for (int mi = 0; mi < 2; ++mi)
#pragma unroll
        for (int kd = 0; kd < 4; ++kd)
            Qa[mi][kd] = *(const bf16x8*)(Qg + (size_t)(b * SS + q0 + mi * 64 + w * 16 + l16) * EE
                                          + h * DD + kd * 32 + quad * 8);

    float m_i[2] = {-INFINITY, -INFINITY};
    float l_i[2] = {0.f, 0.f};
    f32x4 acc_o[2][8];
#pragma unroll
    for (int mi = 0; mi < 2; ++mi)
#pragma unroll
        for (int dt = 0; dt < 8; ++dt) acc_o[mi][dt] = (f32x4){0.f, 0.f, 0.f, 0.f};

    const int ktlast = 2 * qc + 1;
    const int myq[2] = { q0 + w * 16 + l16, q0 + 64 + w * 16 + l16 };

    // ---- swizzled async stage of K (64x128) and Vt (128x64) tiles ----
    auto stage = [&](int kt, int buf) {
#pragma unroll
        for (int it = 0; it < 4; ++it) {
            int ci = it * 256 + tid;          // chunk position in LDS (16B units)
            int r = ci >> 4, pp = ci & 15;
            int c = (pp & 8) | ((pp ^ r) & 7);   // global chunk that belongs here
            gload_lds16(Kg + kgbase + (size_t)(kt * 64 + r) * KVN + c * 8,
                        &Ks[buf][(size_t)(it * 256 + (tid & 192)) * 8]);
        }
#pragma unroll
        for (int it = 0; it < 4; ++it) {
            int ci = it * 256 + tid;
            int r = ci >> 3, pp = ci & 7;
            int c = (pp ^ r) & 7;
            gload_lds16(VtG + vgbase + (size_t)r * SS + kt * 64 + c * 8,
                        &Vt[buf][(size_t)(it * 256 + (tid & 192)) * 8]);
        }
    };

    stage(0, 0);
    int pbuf = 0;

    for (int kt = 0; kt <= ktlast; ++kt) {
        __syncthreads();                 // drains DMA for buf[pbuf]; prev readers done
        if (kt < ktlast) stage(kt + 1, pbuf ^ 1);   // overlaps entire compute phase

        const u16* kb_base = Ks[pbuf];
        const u16* vb_base = Vt[pbuf];
        const bool skip0 = (kt == ktlast);   // mi=0 rows fully masked on last k-tile

        // ---- S^T = K Q^T : lane q=l16, k = kt*64 + kkt*16 + quad*4 + reg ----
        f32x4 sc[2][4];
#pragma unroll
        for (int mi = 0; mi < 2; ++mi)
#pragma unroll
            for (int kkt = 0; kkt < 4; ++kkt) sc[mi][kkt] = (f32x4){0.f, 0.f, 0.f, 0.f};
#pragma unroll
        for (int kkt = 0; kkt < 4; ++kkt) {
            const int R = kkt * 16 + l16;
            bf16x8 kb[4];
#pragma unroll
            for (int kd = 0; kd < 4; ++kd) {
                int c = kd * 4 + quad;
                int pp = (c & 8) | ((c ^ sw) & 7);
                kb[kd] = *(const bf16x8*)&kb_base[(R * 16 + pp) * 8];
            }
#pragma unroll
            for (int kd = 0; kd < 4; ++kd)
                sc[1][kkt] = __builtin_amdgcn_mfma_f32_16x16x32_bf16(kb[kd], Qa[1][kd], sc[1][kkt], 0, 0, 0);
            if (!skip0)
#pragma unroll
                for (int kd = 0; kd < 4; ++kd)
                    sc[0][kkt] = __builtin_amdgcn_mfma_f32_16x16x32_bf16(kb[kd], Qa[0][kd], sc[0][kkt], 0, 0, 0);
        }

        // ---- per-lane online softmax (log2 domain, exp2) ----
        float alpha[2];
#pragma unroll
        for (int mi = 0; mi < 2; ++mi) {
            if (mi == 0 && skip0) { alpha[0] = 1.f; continue; }
            const bool diag = (kt == 2 * qc + mi);
            if (diag) {
                const int kb0 = kt * 64 + quad * 4;
#pragma unroll
                for (int kkt = 0; kkt < 4; ++kkt)
#pragma unroll
                    for (int reg = 0; reg < 4; ++reg)
                        if (kb0 + kkt * 16 + reg > myq[mi]) sc[mi][kkt][reg] = -INFINITY;
            }
            float rowmax = -INFINITY;
#pragma unroll
            for (int kkt = 0; kkt < 4; ++kkt)
#pragma unroll
                for (int reg = 0; reg < 4; ++reg)
                    rowmax = fmaxf(rowmax, sc[mi][kkt][reg]);
            rowmax = fmaxf(rowmax, __shfl_xor(rowmax, 16, 64));
            rowmax = fmaxf(rowmax, __shfl_xor(rowmax, 32, 64));
            float mnew = fmaxf(m_i[mi], rowmax);
            float rsum = 0.f;
#pragma unroll
            for (int kkt = 0; kkt < 4; ++kkt)
#pragma unroll
                for (int reg = 0; reg < 4; ++reg) {
                    float p = exp2f(sc[mi][kkt][reg] - mnew);
                    sc[mi][kkt][reg] = p;
                    rsum += p;
                }
            rsum += __shfl_xor(rsum, 16, 64);
            rsum += __shfl_xor(rsum, 32, 64);
            alpha[mi] = exp2f(m_i[mi] - mnew);
            l_i[mi] = l_i[mi] * alpha[mi] + rsum;
            m_i[mi] = mnew;
            // swizzled packed P^T write (8-B halves of 16-B chunks)
            const int prow = mi * 64 + w * 16 + l16;
#pragma unroll
            for (int kkt = 0; kkt < 4; ++kkt) {
                int ch = (kkt * 2 + (quad >> 1)) ^ sw;
                uint2 pk;
                pk.x = f2bf_pk(sc[mi][kkt][0], sc[mi][kkt][1]);
                pk.y = f2bf_pk(sc[mi][kkt][2], sc[mi][kkt][3]);
                *(uint2*)&Ps[(prow * 8 + ch) * 8 + (quad & 1) * 4] = pk;
            }
        }
        // no barrier: each wave reads only its own Ps rows (lgkmcnt orders it)

        // ---- rescale O ----
#pragma unroll
        for (int mi = 0; mi < 2; ++mi) {
            if (mi == 0 && skip0) continue;
#pragma unroll
            for (int dt = 0; dt < 8; ++dt)
#pragma unroll
                for (int reg = 0; reg < 4; ++reg)
                    acc_o[mi][dt][reg] *= alpha[mi];
        }

        // ---- O^T += V^T P^T ----
#pragma unroll
        for (int ks = 0; ks < 2; ++ks) {
            const int pc = (ks * 4 + quad) ^ sw;
            bf16x8 pb1 = *(const bf16x8*)&Ps[((64 + w * 16 + l16) * 8 + pc) * 8];
            bf16x8 pb0;
            if (!skip0) pb0 = *(const bf16x8*)&Ps[((w * 16 + l16) * 8 + pc) * 8];
#pragma unroll
            for (int dt = 0; dt < 8; ++dt) {
                bf16x8 va = *(const bf16x8*)&vb_base[((dt * 16 + l16) * 8 + pc) * 8];
                acc_o[1][dt] = __builtin_amdgcn_mfma_f32_16x16x32_bf16(va, pb1, acc_o[1][dt], 0, 0, 0);
                if (!skip0)
                    acc_o[0][dt] = __builtin_amdgcn_mfma_f32_16x16x32_bf16(va, pb0, acc_o[0][dt], 0, 0, 0);
            }
        }
        pbuf ^= 1;
    }

    // ---- epilogue: packed ushort4 stores, lane q=l16, d=dt*16+quad*4+reg ----
#pragma unroll
    for (int mi = 0; mi < 2; ++mi) {
        const float linv = 1.f / l_i[mi];
        u16* dst = ctx + (size_t)(b * SS + myq[mi]) * EE + h * DD;
#pragma unroll
        for (int dt = 0; dt < 8; ++dt) {
            ushort4 o;
            o.x = f2bf(acc_o[mi][dt][0] * linv);
            o.y = f2bf(acc_o[mi][dt][1] * linv);
            o.z = f2bf(acc_o[mi][dt][2] * linv);
            o.w = f2bf(acc_o[mi][dt][3] * linv);
            *(ushort4*)&dst[dt * 16 + quad * 4] = o;
        }
    }
}

// ---------------------------------------------------------------------------
extern "C" void kernel_launch(void* const* d_in, const int* in_sizes, int n_in,
                              void* d_out, int out_size, void* d_ws, size_t ws_size,
                              hipStream_t stream) {
    const float* x  = (const float*)d_in[0];
    const float* Wq = (const float*)d_in[1];
    const float* Wk = (const float*)d_in[2];
    const float* Wv = (const float*)d_in[3];
    const float* Wo = (const float*)d_in[4];
    float* out = (float*)d_out;

    const int M = BB * SS;                        // 4096
    u16* xb  = (u16*)d_ws;                        // M*E
    u16* Wqb = xb  + (size_t)M * EE;              // E*E   } contiguous ->
    u16* Wkb = Wqb + (size_t)EE * EE;             // KVN*E }  single 3072-row
    u16* Wvb = Wkb + (size_t)KVN * EE;            // KVN*E }  B matrix
    u16* Wob = Wvb + (size_t)KVN * EE;            // E*E
    u16* Qg  = Wob + (size_t)EE * EE;             // M*E (pre-scaled by QSCALE)
    u16* Kg  = Qg  + (size_t)M * EE;              // M*KVN
    u16* VtG = Kg  + (size_t)M * KVN;             // M*KVN (transposed)
    u16* ctx = VtG + (size_t)M * KVN;             // M*E

    dim3 blk(256);
    cast_all<<<dim3(NB_X + NB_QO + 2 * NB_KV + NB_QO), blk, 0, stream>>>(
        x, Wq, Wk, Wv, Wo, xb, Wqb, Wkb, Wvb, Wob);

    // fused QKV projection: B = [Wq;Wk;Wv] (3072 x 2048)
    gemm_mfma<5><<<dim3(3072 / 128, M / 128), blk, 0, stream>>>(
        xb, Wqb, Qg, Kg, VtG, M, 3072, EE);
    attn_mfma<<<dim3(512), blk, 0, stream>>>(Qg, Kg, VtG, ctx);
    gemm_mfma<0><<<dim3(EE / 128, M / 128), blk, 0, stream>>>(
        ctx, Wob, out, nullptr, nullptr, M, EE, EE);
}